// Round 1
// 134.983 us; speedup vs baseline: 1.0203x; 1.0203x over previous
//
#include <hip/hip_runtime.h>
#include <stdint.h>

// pooled[b,p] = sum_{n in seg b} max_e ( proxy[p,e,:] . x[n,:] );  out = L2-normalized rows.
// P=128, E=32, D=64, B=1024 segments (len 128, 32-aligned starts in bench; ragged handled
// via global-32-aligned tiles + per-column epilogue masks).
//
// R3: break the MFMA/epilogue convoy. R2 issued 16 back-to-back MFMAs (512 cyc of
//     pipe-serialized issue, wave issues nothing else) followed by a ~400-cyc serial
//     epilogue; 2 waves/SIMD phase-lock on the shared MFMA pipe -> MfmaUtil 38%.
//     Now: double-buffered accumulators (P/Q, +64 regs) and the PREVIOUS iteration's
//     epilogue hand-interleaved between the current iteration's 4-MFMA kk-groups:
//       kk0 -> max16(d0), max16(d1); kk1 -> max16(d2), max16(d3);
//       kk2 -> 4x shfl_xor+fmax;     kk3 -> mask/sum/LDS-RMW.
//     Each VALU chunk (~30 ops) fits the 128-cyc pipe-drain shadow of its kk-group,
//     so a single wave keeps the MFMA pipe ~fed. Still __launch_bounds__(256,2):
//     ~240 regs total, inside budget.

typedef short short8 __attribute__((ext_vector_type(8)));
typedef __bf16 bf16x8 __attribute__((ext_vector_type(8)));
typedef float floatx16 __attribute__((ext_vector_type(16)));

#define NELEM 32
#define DIM   64
#define NSEG  1024
#define BROW  36   /* buf row stride in floats: 32 + 4 pad (16B-aligned rows) */

#define MFMA_B16(d, a, b, c) \
  d = __builtin_amdgcn_mfma_f32_32x32x16_bf16((a), (b), (c), 0, 0, 0)

__device__ __forceinline__ unsigned short f32_to_bf16_rne(float f) {
  union { float f; unsigned int u; } v; v.f = f;
  unsigned int r = v.u + 0x7fffu + ((v.u >> 16) & 1u);
  return (unsigned short)(r >> 16);
}

// Block 0: exclusive scan of segment lengths -> offs[0..NSEG].
// Blocks 1..128: shuffle proxy fp32 -> fragment-major bf16 pb2:
//   pb2[ ((p*4 + kk)*64 + lane) * 8 ] = proxy[p][e=lane&31][kk*16 + (lane>>5)*8 .. +8]
__global__ void sc_prep(const float* __restrict__ proxy,
                        const int* __restrict__ index,
                        short* __restrict__ pb2,
                        int* __restrict__ offs) {
  const int bx = blockIdx.x, t = threadIdx.x;
  if (bx == 0) {
    __shared__ int lsum[256];
    const int base = t * 4;
    const int i0 = index[base + 0], i1 = index[base + 1];
    const int i2 = index[base + 2], i3 = index[base + 3];
    const int s = i0 + i1 + i2 + i3;
    lsum[t] = s;
    __syncthreads();
    for (int off = 1; off < 256; off <<= 1) {
      int v = (t >= off) ? lsum[t - off] : 0;
      __syncthreads();
      lsum[t] += v;
      __syncthreads();
    }
    const int ex = lsum[t] - s;
    offs[base + 0] = ex;
    offs[base + 1] = ex + i0;
    offs[base + 2] = ex + i0 + i1;
    offs[base + 3] = ex + i0 + i1 + i2;
    if (t == 255) offs[NSEG] = ex + s;
  } else {
    const int w = t >> 6, lane = t & 63;
    const int task = (bx - 1) * 4 + w;   // 0..511 = (p, kk)
    const int p = task >> 2, kk = task & 3;
    const int l31 = lane & 31, h = lane >> 5;
    const float* src = proxy + (size_t)p * (NELEM * DIM) + l31 * DIM + kk * 16 + h * 8;
    float4 f0 = *(const float4*)(src);
    float4 f1 = *(const float4*)(src + 4);
    short8 fr;
    fr[0] = (short)f32_to_bf16_rne(f0.x);
    fr[1] = (short)f32_to_bf16_rne(f0.y);
    fr[2] = (short)f32_to_bf16_rne(f0.z);
    fr[3] = (short)f32_to_bf16_rne(f0.w);
    fr[4] = (short)f32_to_bf16_rne(f1.x);
    fr[5] = (short)f32_to_bf16_rne(f1.y);
    fr[6] = (short)f32_to_bf16_rne(f1.z);
    fr[7] = (short)f32_to_bf16_rne(f1.w);
    *(short8*)(pb2 + ((size_t)task * 64 + lane) * 8) = fr;  // coalesced 1KB/wave
  }
}

__device__ __forceinline__ float max16(const floatx16& a) {
  float r0 = fmaxf(fmaxf(a[0], a[1]), a[2]);
  float r1 = fmaxf(fmaxf(a[3], a[4]), a[5]);
  float r2 = fmaxf(fmaxf(a[6], a[7]), a[8]);
  float r3 = fmaxf(fmaxf(a[9], a[10]), a[11]);
  float r4 = fmaxf(fmaxf(a[12], a[13]), a[14]);
  float r5 = fmaxf(fmaxf(r0, r1), r2);
  float r6 = fmaxf(fmaxf(r3, r4), a[15]);
  return fmaxf(r5, r6);
}

__global__ __launch_bounds__(256, 2) void sc_main(
    const float* __restrict__ x,
    const short* __restrict__ pb2,
    const int* __restrict__ offs,
    float* __restrict__ out,
    int nrows) {
  __shared__ float buf[128 * BROW];
  __shared__ float red[4];

  const int b = blockIdx.x;
  const int tid = threadIdx.x;
  const int lane = tid & 63;
  const int w = tid >> 6;     // wave w handles p = w + 4i, i in [0,32)
  const int l31 = lane & 31;
  const int h = lane >> 5;

  const int start = offs[b];
  const int end = offs[b + 1];
  const int len = end - start;
  const int first = start >> 5;
  const int ntiles = (len > 0) ? (((end + 31) >> 5) - first) : 0;
  const int npass = (ntiles + 3) >> 2;

  if (ntiles == 0) {
    for (int j = tid; j < 128 * BROW; j += 256) buf[j] = 0.f;
  }

  floatx16 zc;  // permanently-zero C operand
#pragma unroll
  for (int r = 0; r < 16; ++r) zc[r] = 0.f;

  // A lane base: frag(p=w+4i, kk) at pb2 + ((p*4+kk)*64 + lane)*8 shorts
  //            = abase + i*8192 + kk*512  (shorts)
  const short* abase = pb2 + ((size_t)w * 4 * 64 + lane) * 8;

  for (int pass = 0; pass < npass; ++pass) {
    // ---- B-frags: 4 global-aligned 32-row tiles, fp32 -> bf16 in-reg (once per
    // pass, amortized over 32 p-iterations). Out-of-segment columns masked in
    // the epilogue (garbage rows are safe: clamped addresses, per-col cndmask).
    short8 bfrag[4][4];
    bool vmask[4];
#pragma unroll
    for (int t4 = 0; t4 < 4; ++t4) {
      const int tile = first + pass * 4 + t4;
      const int n = tile * 32 + l31;
      vmask[t4] = (n >= start) && (n < end);
      int rn = n < nrows ? n : nrows - 1;  // clamp for safe load
      const float* xr = x + (size_t)rn * DIM + h * 8;
#pragma unroll
      for (int kk = 0; kk < 4; ++kk) {
        float4 f0 = *(const float4*)(xr + kk * 16);
        float4 f1 = *(const float4*)(xr + kk * 16 + 4);
        short8 fr;
        fr[0] = (short)f32_to_bf16_rne(f0.x);
        fr[1] = (short)f32_to_bf16_rne(f0.y);
        fr[2] = (short)f32_to_bf16_rne(f0.z);
        fr[3] = (short)f32_to_bf16_rne(f0.w);
        fr[4] = (short)f32_to_bf16_rne(f1.x);
        fr[5] = (short)f32_to_bf16_rne(f1.y);
        fr[6] = (short)f32_to_bf16_rne(f1.z);
        fr[7] = (short)f32_to_bf16_rne(f1.w);
        bfrag[t4][kk] = fr;
      }
    }

    short8 afA[4], afB[4];
#pragma unroll
    for (int kk = 0; kk < 4; ++kk)
      afA[kk] = *(const short8*)(abase + kk * 512);

    floatx16 p0, p1, p2, p3, q0, q1, q2, q3;

    // ---- prologue: i=0 -> P, prefetch af(1), no epilogue yet
    {
      const short* ap = abase + 8192;
#pragma unroll
      for (int kk = 0; kk < 4; ++kk)
        afB[kk] = *(const short8*)(ap + kk * 512);
#pragma unroll
      for (int kk = 0; kk < 4; ++kk) {
        const bf16x8 a = __builtin_bit_cast(bf16x8, afA[kk]);
        const bf16x8 b0 = __builtin_bit_cast(bf16x8, bfrag[0][kk]);
        const bf16x8 b1 = __builtin_bit_cast(bf16x8, bfrag[1][kk]);
        const bf16x8 b2 = __builtin_bit_cast(bf16x8, bfrag[2][kk]);
        const bf16x8 b3 = __builtin_bit_cast(bf16x8, bfrag[3][kk]);
        if (kk == 0) {
          MFMA_B16(p0, a, b0, zc);
          MFMA_B16(p1, a, b1, zc);
          MFMA_B16(p2, a, b2, zc);
          MFMA_B16(p3, a, b3, zc);
        } else {
          MFMA_B16(p0, a, b0, p0);
          MFMA_B16(p1, a, b1, p1);
          MFMA_B16(p2, a, b2, p2);
          MFMA_B16(p3, a, b3, p3);
        }
      }
    }

    // step(i): issue MFMAs for iteration i into (c0..c3), interleaving the
    // epilogue of iteration i-1 (accs d0..d3) into the kk-group pipe shadows.
    auto step = [&](int i, short8 (&cur)[4], short8 (&nxt)[4], bool pf,
                    floatx16& c0, floatx16& c1, floatx16& c2, floatx16& c3,
                    floatx16& d0, floatx16& d1, floatx16& d2, floatx16& d3) {
      if (pf) {  // double-buffered coalesced A prefetch (next p = +4)
        const short* ap = abase + (size_t)(i + 1) * 8192;
#pragma unroll
        for (int kk = 0; kk < 4; ++kk)
          nxt[kk] = *(const short8*)(ap + kk * 512);
      }
      // ---- kk = 0
      {
        const bf16x8 a = __builtin_bit_cast(bf16x8, cur[0]);
        MFMA_B16(c0, a, __builtin_bit_cast(bf16x8, bfrag[0][0]), zc);
        MFMA_B16(c1, a, __builtin_bit_cast(bf16x8, bfrag[1][0]), zc);
        MFMA_B16(c2, a, __builtin_bit_cast(bf16x8, bfrag[2][0]), zc);
        MFMA_B16(c3, a, __builtin_bit_cast(bf16x8, bfrag[3][0]), zc);
      }
      float n0 = max16(d0);
      float n1 = max16(d1);
      // ---- kk = 1
      {
        const bf16x8 a = __builtin_bit_cast(bf16x8, cur[1]);
        MFMA_B16(c0, a, __builtin_bit_cast(bf16x8, bfrag[0][1]), c0);
        MFMA_B16(c1, a, __builtin_bit_cast(bf16x8, bfrag[1][1]), c1);
        MFMA_B16(c2, a, __builtin_bit_cast(bf16x8, bfrag[2][1]), c2);
        MFMA_B16(c3, a, __builtin_bit_cast(bf16x8, bfrag[3][1]), c3);
      }
      float n2 = max16(d2);
      float n3 = max16(d3);
      // ---- kk = 2
      {
        const bf16x8 a = __builtin_bit_cast(bf16x8, cur[2]);
        MFMA_B16(c0, a, __builtin_bit_cast(bf16x8, bfrag[0][2]), c0);
        MFMA_B16(c1, a, __builtin_bit_cast(bf16x8, bfrag[1][2]), c1);
        MFMA_B16(c2, a, __builtin_bit_cast(bf16x8, bfrag[2][2]), c2);
        MFMA_B16(c3, a, __builtin_bit_cast(bf16x8, bfrag[3][2]), c3);
      }
      n0 = fmaxf(n0, __shfl_xor(n0, 32, 64));
      n1 = fmaxf(n1, __shfl_xor(n1, 32, 64));
      n2 = fmaxf(n2, __shfl_xor(n2, 32, 64));
      n3 = fmaxf(n3, __shfl_xor(n3, 32, 64));
      // ---- kk = 3
      {
        const bf16x8 a = __builtin_bit_cast(bf16x8, cur[3]);
        MFMA_B16(c0, a, __builtin_bit_cast(bf16x8, bfrag[0][3]), c0);
        MFMA_B16(c1, a, __builtin_bit_cast(bf16x8, bfrag[1][3]), c1);
        MFMA_B16(c2, a, __builtin_bit_cast(bf16x8, bfrag[2][3]), c2);
        MFMA_B16(c3, a, __builtin_bit_cast(bf16x8, bfrag[3][3]), c3);
      }
      // mask out-of-segment columns (select, not multiply: garbage may be NaN/inf)
      n0 = vmask[0] ? n0 : 0.f;
      n1 = vmask[1] ? n1 : 0.f;
      n2 = vmask[2] ? n2 : 0.f;
      n3 = vmask[3] ? n3 : 0.f;
      const float s = (n0 + n1) + (n2 + n3);  // partial sum over 4 tiles, col l31
      if (h == 0) {
        const int idx = (w + 4 * (i - 1)) * BROW + l31;
        float prev = (pass == 0) ? 0.f : buf[idx];
        buf[idx] = prev + s;
      }
    };

#pragma unroll 1
    for (int k = 0; k < 15; ++k) {
      const int i = 2 * k + 1;
      step(i, afB, afA, true, q0, q1, q2, q3, p0, p1, p2, p3);
      step(i + 1, afA, afB, true, p0, p1, p2, p3, q0, q1, q2, q3);
    }
    step(31, afB, afA, false, q0, q1, q2, q3, p0, p1, p2, p3);

    // ---- tail epilogue: ip = 31 on Q
    {
      float n0 = max16(q0), n1 = max16(q1), n2 = max16(q2), n3 = max16(q3);
      n0 = fmaxf(n0, __shfl_xor(n0, 32, 64));
      n1 = fmaxf(n1, __shfl_xor(n1, 32, 64));
      n2 = fmaxf(n2, __shfl_xor(n2, 32, 64));
      n3 = fmaxf(n3, __shfl_xor(n3, 32, 64));
      n0 = vmask[0] ? n0 : 0.f;
      n1 = vmask[1] ? n1 : 0.f;
      n2 = vmask[2] ? n2 : 0.f;
      n3 = vmask[3] ? n3 : 0.f;
      const float s = (n0 + n1) + (n2 + n3);
      if (h == 0) {
        const int idx = (w + 4 * 31) * BROW + l31;
        float prev = (pass == 0) ? 0.f : buf[idx];
        buf[idx] = prev + s;
      }
    }
  }
  __syncthreads();

  // Batched 32-col reduction + fused L2-normalize. 2 threads per p.
  const int p2 = tid >> 1, part = tid & 1;
  const float* bp = buf + p2 * BROW + part * 16;
  float4 v0 = *(const float4*)(bp + 0);
  float4 v1 = *(const float4*)(bp + 4);
  float4 v2 = *(const float4*)(bp + 8);
  float4 v3 = *(const float4*)(bp + 12);
  float s16 = ((v0.x + v0.y) + (v0.z + v0.w)) + ((v1.x + v1.y) + (v1.z + v1.w)) +
              ((v2.x + v2.y) + (v2.z + v2.w)) + ((v3.x + v3.y) + (v3.z + v3.w));
  const float s32 = s16 + __shfl_xor(s16, 1, 64);  // pooled[b][p2]

  float sq = part ? 0.f : s32 * s32;
#pragma unroll
  for (int off = 1; off <= 32; off <<= 1) sq += __shfl_xor(sq, off, 64);
  if (lane == 0) red[w] = sq;
  __syncthreads();
  const float ss = (red[0] + red[1]) + (red[2] + red[3]);
  const float inv = 1.f / fmaxf(sqrtf(ss), 1e-12f);
  if (part == 0) out[(b << 7) + p2] = s32 * inv;
}

extern "C" void kernel_launch(void* const* d_in, const int* in_sizes, int n_in,
                              void* d_out, int out_size, void* d_ws, size_t ws_size,
                              hipStream_t stream) {
  (void)n_in; (void)out_size; (void)ws_size;
  const float* x = (const float*)d_in[0];      // [N, 64] fp32
  const float* proxy = (const float*)d_in[1];  // [128, 32, 64] fp32
  const int* index = (const int*)d_in[2];      // [1024] int32
  float* out = (float*)d_out;                  // [1024, 128] fp32
  const int nrows = in_sizes[0] / DIM;

  int* offs = (int*)d_ws;                      // (NSEG+1) ints
  short* pb2 = (short*)((char*)d_ws + 8192);   // 512 KB fragment-major bf16 proxy

  sc_prep<<<129, 256, 0, stream>>>(proxy, index, pb2, offs);
  sc_main<<<NSEG, 256, 0, stream>>>(x, pb2, offs, out, nrows);
}

// Round 2
// 130.858 us; speedup vs baseline: 1.0525x; 1.0315x over previous
//
#include <hip/hip_runtime.h>
#include <stdint.h>

// pooled[b,p] = sum_{n in seg b} max_e ( proxy[p,e,:] . x[n,:] );  out = L2-normalized rows.
// P=128, E=32, D=64, B=1024 segments (len 128, 32-aligned starts in bench; ragged handled
// via global-32-aligned tiles + per-column epilogue masks).
//
// R4: half-iteration software pipeline. R3's full acc double-buffer (P/Q = 128 acc
//     VGPRs) blew the 256-reg budget at 2 waves/SIMD -> ~10KB/block scratch spill
//     (WRITE_SIZE 0.5 -> 11.1 MB), eating the interleave win. Now chains are split
//     into G0={tile0,1}, G1={tile2,3}: G0(i)'s 8-MFMA issue hides epi(G1(i-1)),
//     G1(i)'s issue hides epi(G0(i)). Each group's accs are consumed before its
//     next issue -> only 64 acc regs total. ~196 regs: fits, no spill.
//     Epilogue chunk (~25 VALU ops, ~50cyc) per 256-cyc MFMA-issue shadow.

typedef short short8 __attribute__((ext_vector_type(8)));
typedef __bf16 bf16x8 __attribute__((ext_vector_type(8)));
typedef float floatx16 __attribute__((ext_vector_type(16)));

#define NELEM 32
#define DIM   64
#define NSEG  1024
#define BROW  36   /* buf row stride in floats: 32 + 4 pad (16B-aligned rows) */

#define MFMA_B16(d, a, b, c) \
  d = __builtin_amdgcn_mfma_f32_32x32x16_bf16((a), (b), (c), 0, 0, 0)
#define BC(v) __builtin_bit_cast(bf16x8, v)

__device__ __forceinline__ unsigned short f32_to_bf16_rne(float f) {
  union { float f; unsigned int u; } v; v.f = f;
  unsigned int r = v.u + 0x7fffu + ((v.u >> 16) & 1u);
  return (unsigned short)(r >> 16);
}

// Block 0: exclusive scan of segment lengths -> offs[0..NSEG].
// Blocks 1..128: shuffle proxy fp32 -> fragment-major bf16 pb2:
//   pb2[ ((p*4 + kk)*64 + lane) * 8 ] = proxy[p][e=lane&31][kk*16 + (lane>>5)*8 .. +8]
__global__ void sc_prep(const float* __restrict__ proxy,
                        const int* __restrict__ index,
                        short* __restrict__ pb2,
                        int* __restrict__ offs) {
  const int bx = blockIdx.x, t = threadIdx.x;
  if (bx == 0) {
    __shared__ int lsum[256];
    const int base = t * 4;
    const int i0 = index[base + 0], i1 = index[base + 1];
    const int i2 = index[base + 2], i3 = index[base + 3];
    const int s = i0 + i1 + i2 + i3;
    lsum[t] = s;
    __syncthreads();
    for (int off = 1; off < 256; off <<= 1) {
      int v = (t >= off) ? lsum[t - off] : 0;
      __syncthreads();
      lsum[t] += v;
      __syncthreads();
    }
    const int ex = lsum[t] - s;
    offs[base + 0] = ex;
    offs[base + 1] = ex + i0;
    offs[base + 2] = ex + i0 + i1;
    offs[base + 3] = ex + i0 + i1 + i2;
    if (t == 255) offs[NSEG] = ex + s;
  } else {
    const int w = t >> 6, lane = t & 63;
    const int task = (bx - 1) * 4 + w;   // 0..511 = (p, kk)
    const int p = task >> 2, kk = task & 3;
    const int l31 = lane & 31, h = lane >> 5;
    const float* src = proxy + (size_t)p * (NELEM * DIM) + l31 * DIM + kk * 16 + h * 8;
    float4 f0 = *(const float4*)(src);
    float4 f1 = *(const float4*)(src + 4);
    short8 fr;
    fr[0] = (short)f32_to_bf16_rne(f0.x);
    fr[1] = (short)f32_to_bf16_rne(f0.y);
    fr[2] = (short)f32_to_bf16_rne(f0.z);
    fr[3] = (short)f32_to_bf16_rne(f0.w);
    fr[4] = (short)f32_to_bf16_rne(f1.x);
    fr[5] = (short)f32_to_bf16_rne(f1.y);
    fr[6] = (short)f32_to_bf16_rne(f1.z);
    fr[7] = (short)f32_to_bf16_rne(f1.w);
    *(short8*)(pb2 + ((size_t)task * 64 + lane) * 8) = fr;  // coalesced 1KB/wave
  }
}

__device__ __forceinline__ float max16(const floatx16& a) {
  float r0 = fmaxf(fmaxf(a[0], a[1]), a[2]);
  float r1 = fmaxf(fmaxf(a[3], a[4]), a[5]);
  float r2 = fmaxf(fmaxf(a[6], a[7]), a[8]);
  float r3 = fmaxf(fmaxf(a[9], a[10]), a[11]);
  float r4 = fmaxf(fmaxf(a[12], a[13]), a[14]);
  float r5 = fmaxf(fmaxf(r0, r1), r2);
  float r6 = fmaxf(fmaxf(r3, r4), a[15]);
  return fmaxf(r5, r6);
}

__global__ __launch_bounds__(256, 2) void sc_main(
    const float* __restrict__ x,
    const short* __restrict__ pb2,
    const int* __restrict__ offs,
    float* __restrict__ out,
    int nrows) {
  __shared__ float buf[128 * BROW];
  __shared__ float red[4];

  const int b = blockIdx.x;
  const int tid = threadIdx.x;
  const int lane = tid & 63;
  const int w = tid >> 6;     // wave w handles p = w + 4i, i in [0,32)
  const int l31 = lane & 31;
  const int h = lane >> 5;

  const int start = offs[b];
  const int end = offs[b + 1];
  const int len = end - start;
  const int first = start >> 5;
  const int ntiles = (len > 0) ? (((end + 31) >> 5) - first) : 0;
  const int npass = (ntiles + 3) >> 2;

  if (ntiles == 0) {
    for (int j = tid; j < 128 * BROW; j += 256) buf[j] = 0.f;
  }

  floatx16 zc;  // permanently-zero C operand
#pragma unroll
  for (int r = 0; r < 16; ++r) zc[r] = 0.f;

  // A lane base: frag(p=w+4i, kk) at pb2 + ((p*4+kk)*64 + lane)*8 shorts
  //            = abase + i*8192 + kk*512  (shorts)
  const short* abase = pb2 + ((size_t)w * 4 * 64 + lane) * 8;

  for (int pass = 0; pass < npass; ++pass) {
    // ---- B-frags: 4 global-aligned 32-row tiles, fp32 -> bf16 in-reg (once per
    // pass, amortized over 32 p-iterations). Out-of-segment columns masked in
    // the epilogue (garbage rows are safe: clamped addresses, per-col cndmask).
    short8 bfrag[4][4];
    bool vmask[4];
#pragma unroll
    for (int t4 = 0; t4 < 4; ++t4) {
      const int tile = first + pass * 4 + t4;
      const int n = tile * 32 + l31;
      vmask[t4] = (n >= start) && (n < end);
      int rn = n < nrows ? n : nrows - 1;  // clamp for safe load
      const float* xr = x + (size_t)rn * DIM + h * 8;
#pragma unroll
      for (int kk = 0; kk < 4; ++kk) {
        float4 f0 = *(const float4*)(xr + kk * 16);
        float4 f1 = *(const float4*)(xr + kk * 16 + 4);
        short8 fr;
        fr[0] = (short)f32_to_bf16_rne(f0.x);
        fr[1] = (short)f32_to_bf16_rne(f0.y);
        fr[2] = (short)f32_to_bf16_rne(f0.z);
        fr[3] = (short)f32_to_bf16_rne(f0.w);
        fr[4] = (short)f32_to_bf16_rne(f1.x);
        fr[5] = (short)f32_to_bf16_rne(f1.y);
        fr[6] = (short)f32_to_bf16_rne(f1.z);
        fr[7] = (short)f32_to_bf16_rne(f1.w);
        bfrag[t4][kk] = fr;
      }
    }

    short8 afA[4], afB[4];
    floatx16 xa, xb, ya, yb;  // G0 / G1 accumulators (single set each)
    float n0 = 0.f, n1 = 0.f; // G0 epilogue partials, carried one half-step

    // g0(i): issue G0 (tiles 0,1) MFMAs for iteration i from cur; optional
    //        prefetch of af(i+1) into nxt; epilogue of G1(i-1) (ya,yb) in the
    //        issue shadows -> combine with carried n0,n1, LDS-RMW row (i-1).
    auto g0 = [&](int i, short8 (&cur)[4], short8 (&nxt)[4], bool pf, bool epi,
                  float pn0, float pn1) {
      if (pf) {  // double-buffered coalesced A prefetch (next p = +4)
        const short* ap = abase + (size_t)(i + 1) * 8192;
#pragma unroll
        for (int kk = 0; kk < 4; ++kk)
          nxt[kk] = *(const short8*)(ap + kk * 512);
      }
      float m2, m3;
      {
        const bf16x8 a = BC(cur[0]);
        MFMA_B16(xa, a, BC(bfrag[0][0]), zc);
        MFMA_B16(xb, a, BC(bfrag[1][0]), zc);
      }
      if (epi) m2 = max16(ya);
      {
        const bf16x8 a = BC(cur[1]);
        MFMA_B16(xa, a, BC(bfrag[0][1]), xa);
        MFMA_B16(xb, a, BC(bfrag[1][1]), xb);
      }
      if (epi) m3 = max16(yb);
      {
        const bf16x8 a = BC(cur[2]);
        MFMA_B16(xa, a, BC(bfrag[0][2]), xa);
        MFMA_B16(xb, a, BC(bfrag[1][2]), xb);
      }
      if (epi) {
        m2 = fmaxf(m2, __shfl_xor(m2, 32, 64));
        m3 = fmaxf(m3, __shfl_xor(m3, 32, 64));
      }
      {
        const bf16x8 a = BC(cur[3]);
        MFMA_B16(xa, a, BC(bfrag[0][3]), xa);
        MFMA_B16(xb, a, BC(bfrag[1][3]), xb);
      }
      if (epi) {
        // mask out-of-segment columns (select, not multiply: garbage may be NaN/inf)
        m2 = vmask[2] ? m2 : 0.f;
        m3 = vmask[3] ? m3 : 0.f;
        const float s = (pn0 + pn1) + (m2 + m3);
        if (h == 0) {
          const int idx = (w + 4 * (i - 1)) * BROW + l31;
          float prev = (pass == 0) ? 0.f : buf[idx];
          buf[idx] = prev + s;
        }
      }
    };

    // g1(i): issue G1 (tiles 2,3) MFMAs from cur; epilogue of G0(i) (xa,xb)
    //        in the issue shadows -> n0,n1 (masked), carried to next g0.
    auto g1 = [&](short8 (&cur)[4]) {
      float m0, m1;
      {
        const bf16x8 a = BC(cur[0]);
        MFMA_B16(ya, a, BC(bfrag[2][0]), zc);
        MFMA_B16(yb, a, BC(bfrag[3][0]), zc);
      }
      m0 = max16(xa);
      {
        const bf16x8 a = BC(cur[1]);
        MFMA_B16(ya, a, BC(bfrag[2][1]), ya);
        MFMA_B16(yb, a, BC(bfrag[3][1]), yb);
      }
      m1 = max16(xb);
      {
        const bf16x8 a = BC(cur[2]);
        MFMA_B16(ya, a, BC(bfrag[2][2]), ya);
        MFMA_B16(yb, a, BC(bfrag[3][2]), yb);
      }
      m0 = fmaxf(m0, __shfl_xor(m0, 32, 64));
      m1 = fmaxf(m1, __shfl_xor(m1, 32, 64));
      {
        const bf16x8 a = BC(cur[3]);
        MFMA_B16(ya, a, BC(bfrag[2][3]), ya);
        MFMA_B16(yb, a, BC(bfrag[3][3]), yb);
      }
      n0 = vmask[0] ? m0 : 0.f;
      n1 = vmask[1] ? m1 : 0.f;
    };

    // prologue: load af(0), prefetch af(1)
#pragma unroll
    for (int kk = 0; kk < 4; ++kk)
      afA[kk] = *(const short8*)(abase + kk * 512);
    {
      const short* ap = abase + 8192;
#pragma unroll
      for (int kk = 0; kk < 4; ++kk)
        afB[kk] = *(const short8*)(ap + kk * 512);
    }
    g0(0, afA, afB, false, false, 0.f, 0.f);  // G0(0), no epilogue yet
    g1(afA);                                  // G1(0) + epi(G0(0))

#pragma unroll 1
    for (int k = 0; k < 15; ++k) {
      const int i = 2 * k + 1;
      g0(i, afB, afA, true, true, n0, n1);      // + epi(G1(i-1)) + finish(i-1)
      g1(afB);                                  // + epi(G0(i))
      g0(i + 1, afA, afB, true, true, n0, n1);  // + epi(G1(i)) + finish(i)
      g1(afA);                                  // + epi(G0(i+1))
    }
    g0(31, afB, afA, false, true, n0, n1);      // + epi(G1(30)) + finish(30)
    g1(afB);                                    // + epi(G0(31))

    // tail: epilogue of G1(31) + finish(31)
    {
      float m2 = max16(ya), m3 = max16(yb);
      m2 = fmaxf(m2, __shfl_xor(m2, 32, 64));
      m3 = fmaxf(m3, __shfl_xor(m3, 32, 64));
      m2 = vmask[2] ? m2 : 0.f;
      m3 = vmask[3] ? m3 : 0.f;
      const float s = (n0 + n1) + (m2 + m3);
      if (h == 0) {
        const int idx = (w + 4 * 31) * BROW + l31;
        float prev = (pass == 0) ? 0.f : buf[idx];
        buf[idx] = prev + s;
      }
    }
  }
  __syncthreads();

  // Batched 32-col reduction + fused L2-normalize. 2 threads per p.
  const int p2 = tid >> 1, part = tid & 1;
  const float* bp = buf + p2 * BROW + part * 16;
  float4 v0 = *(const float4*)(bp + 0);
  float4 v1 = *(const float4*)(bp + 4);
  float4 v2 = *(const float4*)(bp + 8);
  float4 v3 = *(const float4*)(bp + 12);
  float s16 = ((v0.x + v0.y) + (v0.z + v0.w)) + ((v1.x + v1.y) + (v1.z + v1.w)) +
              ((v2.x + v2.y) + (v2.z + v2.w)) + ((v3.x + v3.y) + (v3.z + v3.w));
  const float s32 = s16 + __shfl_xor(s16, 1, 64);  // pooled[b][p2]

  float sq = part ? 0.f : s32 * s32;
#pragma unroll
  for (int off = 1; off <= 32; off <<= 1) sq += __shfl_xor(sq, off, 64);
  if (lane == 0) red[w] = sq;
  __syncthreads();
  const float ss = (red[0] + red[1]) + (red[2] + red[3]);
  const float inv = 1.f / fmaxf(sqrtf(ss), 1e-12f);
  if (part == 0) out[(b << 7) + p2] = s32 * inv;
}

extern "C" void kernel_launch(void* const* d_in, const int* in_sizes, int n_in,
                              void* d_out, int out_size, void* d_ws, size_t ws_size,
                              hipStream_t stream) {
  (void)n_in; (void)out_size; (void)ws_size;
  const float* x = (const float*)d_in[0];      // [N, 64] fp32
  const float* proxy = (const float*)d_in[1];  // [128, 32, 64] fp32
  const int* index = (const int*)d_in[2];      // [1024] int32
  float* out = (float*)d_out;                  // [1024, 128] fp32
  const int nrows = in_sizes[0] / DIM;

  int* offs = (int*)d_ws;                      // (NSEG+1) ints
  short* pb2 = (short*)((char*)d_ws + 8192);   // 512 KB fragment-major bf16 proxy

  sc_prep<<<129, 256, 0, stream>>>(proxy, index, pb2, offs);
  sc_main<<<NSEG, 256, 0, stream>>>(x, pb2, offs, out, nrows);
}